// Round 4
// baseline (1302.445 us; speedup 1.0000x reference)
//
#include <hip/hip_runtime.h>

#define N_PMT 180
#define N_CLUSTERS 128
#define NVOX 262144
#define VPB 1024             // voxels per k4 block (per half)
#define K4_THREADS 1024
#define K4_WAVES 16
#define ACC_HALF 11520       // 128 clusters * 90 pmts
#define OUT_ELEMS (N_CLUSTERS * N_PMT)

// ---- workspace layout (bytes) ----
#define WS_OFFSC   0u          // int[129]
#define WS_DXC     1024u       // float[128]
#define WS_SCANNED 2048u       // int[NVOX]
#define WS_BSUM    1050624u    // int[1024]
#define WS_BBASE   1054720u    // int[1024]
#define WS_OFFS    1058816u    // int[NVOX+1]
#define WS_CURSOR  2107648u    // int[NVOX]  (doubles as k1's count)
#define WS_VQ      3156224u    // uint2[n]
#define WS_ENT     11544832u   // uint2[n]
#define WS_PART    19933440u   // float[512 * ACC_HALF]
#define WS_NEED_ATOMIC 19933440ull
#define WS_NEED_PART   43526400ull

// ---------------- prep: clip dx, cluster offsets ----------------
__global__ void prep_kernel(const float* __restrict__ dx,
                            const int* __restrict__ sizes,
                            const float* __restrict__ dx_ranges,
                            int* __restrict__ offsC,
                            float* __restrict__ dxc) {
    __shared__ int s[N_CLUSTERS];
    const int t = threadIdx.x;      // 128 threads
    s[t] = sizes[t];
    float lo = dx_ranges[2 * t];
    float hi = dx_ranges[2 * t + 1];
    dxc[t] = fminf(fmaxf(dx[t], lo), hi);
    __syncthreads();
    int acc = 0;
    for (int i = 0; i < t; ++i) acc += s[i];
    offsC[t] = acc;
    if (t == N_CLUSTERS - 1) offsC[N_CLUSTERS] = acc + s[t];
}

// ---------------- k1: voxelize + histogram ----------------
__global__ void k1_voxelize(const float4* __restrict__ batch,
                            const int* __restrict__ offsC,
                            const float* __restrict__ dxc,
                            int n, uint2* __restrict__ vq,
                            int* __restrict__ count) {
    int i = blockIdx.x * 256 + threadIdx.x;
    if (i >= n) return;
    int lo = 0, hi = N_CLUSTERS - 1;
    #pragma unroll
    for (int s = 0; s < 7; ++s) {
        int mid = (lo + hi + 1) >> 1;
        if (i >= offsC[mid]) lo = mid; else hi = mid - 1;
    }
    const int c = lo;
    float4 pd = batch[i];
    float x = pd.x + dxc[c];
    int ix = max(0, min(63, (int)floorf(x)));
    int iy = max(0, min(63, (int)floorf(pd.y)));
    int iz = max(0, min(63, (int)floorf(pd.z)));
    int vox = ix + 64 * (iy + 64 * iz);
    vq[i] = make_uint2((unsigned)vox | ((unsigned)c << 18), __float_as_uint(pd.w));
    atomicAdd(&count[vox], 1);
}

// ---------------- k2: 3-stage exclusive scan of count -> offs ----------------
__global__ void k2a_scan(const int* __restrict__ count,
                         int* __restrict__ scanned,
                         int* __restrict__ bsum) {
    __shared__ int s[256];
    const int b = blockIdx.x, t = threadIdx.x, i = b * 256 + t;
    int x = count[i];
    s[t] = x; __syncthreads();
    for (int d = 1; d < 256; d <<= 1) {
        int v_ = (t >= d) ? s[t - d] : 0; __syncthreads();
        s[t] += v_; __syncthreads();
    }
    scanned[i] = s[t] - x;
    if (t == 255) bsum[b] = s[255];
}

__global__ void k2b_scan(const int* __restrict__ bsum, int* __restrict__ bbase) {
    __shared__ int s[1024];
    const int t = threadIdx.x;
    int x = bsum[t];
    s[t] = x; __syncthreads();
    for (int d = 1; d < 1024; d <<= 1) {
        int v_ = (t >= d) ? s[t - d] : 0; __syncthreads();
        s[t] += v_; __syncthreads();
    }
    bbase[t] = s[t] - x;
}

__global__ void k2c_fix(const int* __restrict__ scanned,
                        const int* __restrict__ bbase,
                        int* __restrict__ offs,
                        int* __restrict__ cursor, int total) {
    const int b = blockIdx.x, t = threadIdx.x, i = b * 256 + t;
    int o = scanned[i] + bbase[b];
    offs[i] = o;
    cursor[i] = o;
    if (i == NVOX - 1) offs[NVOX] = total;
}

// ---------------- k3: scatter points into CSR ----------------
__global__ void k3_scatter(const uint2* __restrict__ vq,
                           int* __restrict__ cursor,
                           uint2* __restrict__ entries, int n) {
    int i = blockIdx.x * 256 + threadIdx.x;
    if (i >= n) return;
    uint2 e = vq[i];
    int vox = (int)(e.x & 0x3FFFFu);
    unsigned c = e.x >> 18;
    int pos = atomicAdd(&cursor[vox], 1);
    entries[pos] = make_uint2(e.y, c);
}

// ---------------- k4: voxel-major accumulate into LDS ----------------
__global__ __launch_bounds__(K4_THREADS) void k4_accum(
    const float* __restrict__ vis,
    const int* __restrict__ offs,
    const uint2* __restrict__ entries,
    float* __restrict__ out,
    float* __restrict__ partial, int mode) {

    __shared__ float acc[ACC_HALF];
    const int h  = blockIdx.x & 1;    // pmt half: [h*90, h*90+90)
    const int vb = blockIdx.x >> 1;   // voxel chunk
    for (int j = threadIdx.x; j < ACC_HALF; j += K4_THREADS) acc[j] = 0.f;
    __syncthreads();

    const int wv = threadIdx.x >> 6;
    const int l  = threadIdx.x & 63;
    const bool lB = (l < 26);         // second part: pmts h*90 + 64 + l
    const int v0 = vb * VPB + wv * (VPB / K4_WAVES);
    const int v1 = v0 + (VPB / K4_WAVES);
    const int hoff = h * 90;

    for (int v = v0; v < v1; ++v) {
        int e0 = offs[v], e1 = offs[v + 1];
        if (e0 >= e1) continue;                 // wave-uniform branch
        const float* rowp = vis + (size_t)v * N_PMT + hoff;
        float rA = rowp[l];                     // lanes 0..63 -> pmts 0..63 of half
        float rB = lB ? rowp[64 + l] : 0.f;     // lanes 0..25 -> pmts 64..89
        for (int e = e0; e < e1; ++e) {
            uint2 ent = entries[e];             // uniform address -> broadcast
            float q = __uint_as_float(ent.x);
            int   c = (int)ent.y;
            float* ab = &acc[c * 90];
            atomicAdd(&ab[l], rA * q);          // stride-1 across lanes: <=2-way
            if (lB) atomicAdd(&ab[64 + l], rB * q);
        }
    }
    __syncthreads();

    if (mode == 0) {
        float* dst = partial + (size_t)blockIdx.x * ACC_HALF;
        for (int j = threadIdx.x; j < ACC_HALF; j += K4_THREADS) dst[j] = acc[j];
    } else {
        for (int j = threadIdx.x; j < ACC_HALF; j += K4_THREADS) {
            int c = j / 90, pp = j - c * 90;
            atomicAdd(&out[c * N_PMT + hoff + pp], acc[j]);
        }
    }
}

// ---------------- k5: reduce partials ----------------
__global__ void k5_reduce(const float* __restrict__ partial, float* __restrict__ out) {
    const int ob = blockIdx.x % 90;   // out chunk of 256
    const int vb = blockIdx.x / 90;   // 8 groups of 32 voxel-chunks
    const int o = ob * 256 + threadIdx.x;       // 0..23039
    const int c = o / N_PMT, p = o - c * N_PMT;
    const int h = p / 90, pp = p - h * 90;
    float s = 0.f;
    const int base = vb * 32;
    #pragma unroll 8
    for (int k = 0; k < 32; ++k) {
        int vc = base + k;
        s += partial[(size_t)(vc * 2 + h) * ACC_HALF + c * 90 + pp];
    }
    atomicAdd(&out[o], s);
}

// ---------------- fallback (point-major gather, R3 structure) ----------------
#define BPC 16
#define BLOCK 256
#define NWAVE (BLOCK / 64)
__global__ __launch_bounds__(BLOCK) void gather_kernel(
    const float4* __restrict__ batch,
    const float4* __restrict__ vis4,
    const int*    __restrict__ offsets,
    const float*  __restrict__ dxc,
    float* __restrict__ out) {
    const int b = blockIdx.x;
    const int c = b / BPC, sub = b % BPC;
    const int start = offsets[c], end = offsets[c + 1];
    const int count = end - start;
    const int chunk = (count + BPC - 1) / BPC;
    const int s0 = start + sub * chunk;
    const int s1 = min(s0 + chunk, end);
    const int wave = threadIdx.x >> 6, lane = threadIdx.x & 63;
    const int wtotal = s1 - s0;
    const int per = (wtotal + NWAVE - 1) / NWAVE;
    const int ws0 = s0 + wave * per;
    const int ws1 = min(ws0 + per, s1);
    const float dxc_c = dxc[c];
    const bool active = (lane < 45);
    float4 accE = {0.f, 0.f, 0.f, 0.f};
    for (int base = ws0; base < ws1; base += 64) {
        const int p = base + lane;
        float q = 0.f; int vox = 0;
        if (p < ws1) {
            float4 pd = batch[p];
            int ix = max(0, min(63, (int)floorf(pd.x + dxc_c)));
            int iy = max(0, min(63, (int)floorf(pd.y)));
            int iz = max(0, min(63, (int)floorf(pd.z)));
            vox = ix + 64 * (iy + 64 * iz);
            q = pd.w;
        }
        #pragma unroll
        for (int j = 0; j < 64; ++j) {
            const int   v  = __builtin_amdgcn_readlane(vox, j);
            const float qj = __uint_as_float(__builtin_amdgcn_readlane(__float_as_uint(q), j));
            if (active) {
                float4 r = vis4[(size_t)v * 45 + lane];
                accE.x = fmaf(r.x, qj, accE.x);
                accE.y = fmaf(r.y, qj, accE.y);
                accE.z = fmaf(r.z, qj, accE.z);
                accE.w = fmaf(r.w, qj, accE.w);
            }
        }
    }
    __shared__ float sacc[N_PMT];
    for (int i = threadIdx.x; i < N_PMT; i += BLOCK) sacc[i] = 0.f;
    __syncthreads();
    if (active) {
        atomicAdd(&sacc[lane * 4 + 0], accE.x);
        atomicAdd(&sacc[lane * 4 + 1], accE.y);
        atomicAdd(&sacc[lane * 4 + 2], accE.z);
        atomicAdd(&sacc[lane * 4 + 3], accE.w);
    }
    __syncthreads();
    for (int i = threadIdx.x; i < N_PMT; i += BLOCK)
        atomicAdd(&out[c * N_PMT + i], sacc[i]);
}

extern "C" void kernel_launch(void* const* d_in, const int* in_sizes, int n_in,
                              void* d_out, int out_size, void* d_ws, size_t ws_size,
                              hipStream_t stream) {
    const float* dx        = (const float*)d_in[0];
    const float* batch     = (const float*)d_in[1];
    const int*   sizes     = (const int*)d_in[2];
    const float* dx_ranges = (const float*)d_in[3];
    const float* vis       = (const float*)d_in[4];
    float* out = (float*)d_out;
    char*  wsb = (char*)d_ws;
    const int n = in_sizes[1] / 4;   // total points

    int*   offsC   = (int*)(wsb + WS_OFFSC);
    float* dxc     = (float*)(wsb + WS_DXC);
    int*   scanned = (int*)(wsb + WS_SCANNED);
    int*   bsum    = (int*)(wsb + WS_BSUM);
    int*   bbase   = (int*)(wsb + WS_BBASE);
    int*   offs    = (int*)(wsb + WS_OFFS);
    int*   cursor  = (int*)(wsb + WS_CURSOR);  // also k1's count
    uint2* vq      = (uint2*)(wsb + WS_VQ);
    uint2* entries = (uint2*)(wsb + WS_ENT);
    float* part    = (float*)(wsb + WS_PART);

    hipMemsetAsync(out, 0, (size_t)out_size * sizeof(float), stream);
    prep_kernel<<<1, N_CLUSTERS, 0, stream>>>(dx, sizes, dx_ranges, offsC, dxc);

    if (ws_size >= WS_NEED_ATOMIC) {
        const int mode = (ws_size >= WS_NEED_PART) ? 0 : 1;
        hipMemsetAsync(cursor, 0, NVOX * sizeof(int), stream);
        k1_voxelize<<<(n + 255) / 256, 256, 0, stream>>>(
            (const float4*)batch, offsC, dxc, n, vq, cursor);
        k2a_scan<<<NVOX / 256, 256, 0, stream>>>(cursor, scanned, bsum);
        k2b_scan<<<1, 1024, 0, stream>>>(bsum, bbase);
        k2c_fix<<<NVOX / 256, 256, 0, stream>>>(scanned, bbase, offs, cursor, n);
        k3_scatter<<<(n + 255) / 256, 256, 0, stream>>>(vq, cursor, entries, n);
        k4_accum<<<(NVOX / VPB) * 2, K4_THREADS, 0, stream>>>(
            vis, offs, entries, out, part, mode);
        if (mode == 0)
            k5_reduce<<<720, 256, 0, stream>>>(part, out);
    } else {
        gather_kernel<<<N_CLUSTERS * BPC, BLOCK, 0, stream>>>(
            (const float4*)batch, (const float4*)vis, offsC, dxc, out);
    }
}

// Round 5
// 340.685 us; speedup vs baseline: 3.8230x; 3.8230x over previous
//
#include <hip/hip_runtime.h>

#define N_PMT 180
#define N_PMT4 45          // 180 floats = 45 float4 per vis row (720 B, 16B-aligned)
#define N_CLUSTERS 128
#define NBINS 512          // sort buckets: vox >> 9 (~360 KB of vis per bucket)
#define BPC 16             // gather blocks per cluster
#define BLOCK 256
#define NWAVE (BLOCK / 64)
#define MLP 8              // row loads in flight per wave

// ---- workspace layout (bytes) ----
// 0       : int   offsC[N_CLUSTERS+1]
// 1024    : float dxc[N_CLUSTERS]
// 2048    : uint2 vq[n]        (vox, q_bits)  cluster-contiguous
// 2048+8n : uint2 sorted[n]    (vox, q_bits)  bucket-sorted within cluster

__global__ void prep_kernel(const float* __restrict__ dx,
                            const int* __restrict__ sizes,
                            const float* __restrict__ dx_ranges,
                            int* __restrict__ offsC,
                            float* __restrict__ dxc) {
    __shared__ int s[N_CLUSTERS];
    const int t = threadIdx.x;      // 128 threads
    s[t] = sizes[t];
    float lo = dx_ranges[2 * t];
    float hi = dx_ranges[2 * t + 1];
    dxc[t] = fminf(fmaxf(dx[t], lo), hi);
    __syncthreads();
    int acc = 0;
    for (int i = 0; i < t; ++i) acc += s[i];
    offsC[t] = acc;
    if (t == N_CLUSTERS - 1) offsC[N_CLUSTERS] = acc + s[t];
}

__global__ void k1_voxelize(const float4* __restrict__ batch,
                            const int* __restrict__ offsC,
                            const float* __restrict__ dxc,
                            int n, uint2* __restrict__ vq) {
    int i = blockIdx.x * 256 + threadIdx.x;
    if (i >= n) return;
    int lo = 0, hi = N_CLUSTERS - 1;
    #pragma unroll
    for (int s = 0; s < 7; ++s) {
        int mid = (lo + hi + 1) >> 1;
        if (i >= offsC[mid]) lo = mid; else hi = mid - 1;
    }
    float4 pd = batch[i];
    int ix = max(0, min(63, (int)floorf(pd.x + dxc[lo])));
    int iy = max(0, min(63, (int)floorf(pd.y)));
    int iz = max(0, min(63, (int)floorf(pd.z)));
    vq[i] = make_uint2((unsigned)(ix + 64 * (iy + 64 * iz)), __float_as_uint(pd.w));
}

// one block per cluster: single-pass counting sort by vox>>9 (int LDS atomics only)
__global__ __launch_bounds__(1024) void ksort(const int* __restrict__ offsC,
                                              const uint2* __restrict__ vq,
                                              uint2* __restrict__ sorted) {
    __shared__ int hist[NBINS], sa[NBINS], sb[NBINS], cur[NBINS];
    const int c = blockIdx.x, t = threadIdx.x;
    const int e0 = offsC[c], e1 = offsC[c + 1], cnt = e1 - e0;
    if (t < NBINS) hist[t] = 0;
    __syncthreads();
    for (int i = t; i < cnt; i += 1024)
        atomicAdd(&hist[vq[e0 + i].x >> 9], 1);
    __syncthreads();
    if (t < NBINS) sa[t] = hist[t];
    __syncthreads();
    int* src = sa; int* dst = sb;
    for (int d = 1; d < NBINS; d <<= 1) {
        if (t < NBINS) dst[t] = src[t] + (t >= d ? src[t - d] : 0);
        __syncthreads();
        int* tmp = src; src = dst; dst = tmp;
    }
    if (t < NBINS) cur[t] = src[t] - hist[t];   // exclusive scan
    __syncthreads();
    for (int i = t; i < cnt; i += 1024) {
        uint2 e = vq[e0 + i];
        int pos = atomicAdd(&cur[e.x >> 9], 1);
        sorted[e0 + pos] = e;
    }
}

__global__ __launch_bounds__(BLOCK) void k_gather(
    const uint2*  __restrict__ sorted,
    const float4* __restrict__ vis4,
    const int*    __restrict__ offsC,
    float* __restrict__ out) {

    const int c   = blockIdx.x & (N_CLUSTERS - 1);  // c fastest: same-region blocks adjacent
    const int sub = blockIdx.x >> 7;
    const int start = offsC[c], end = offsC[c + 1];
    const int count = end - start;
    const int chunk = (count + BPC - 1) / BPC;
    const int s0 = start + sub * chunk;
    const int s1 = min(s0 + chunk, end);

    const int wave = threadIdx.x >> 6, lane = threadIdx.x & 63;
    const int wtotal = s1 - s0;
    const int per = (wtotal + NWAVE - 1) / NWAVE;
    const int ws0 = s0 + wave * per;
    const int ws1 = min(ws0 + per, s1);

    const int lclamp = min(lane, N_PMT4 - 1);    // branchless: lanes 45..63 dup lane 44

    float4 accE = {0.f, 0.f, 0.f, 0.f};
    float4 accO = {0.f, 0.f, 0.f, 0.f};

    for (int base = ws0; base < ws1; base += 64) {
        const int p = base + lane;
        uint2 se = (p < ws1) ? sorted[p] : make_uint2(0u, 0u);  // pad: q=0
        const int   vox = (int)se.x;
        const float q   = __uint_as_float(se.y);
        #pragma unroll
        for (int j0 = 0; j0 < 64; j0 += MLP) {
            int vs[MLP]; float qs[MLP]; float4 r[MLP];
            #pragma unroll
            for (int jj = 0; jj < MLP; ++jj) {
                vs[jj] = __builtin_amdgcn_readlane(vox, j0 + jj);
                qs[jj] = __uint_as_float(
                    __builtin_amdgcn_readlane(__float_as_uint(q), j0 + jj));
            }
            #pragma unroll
            for (int jj = 0; jj < MLP; ++jj)
                r[jj] = vis4[(size_t)vs[jj] * N_PMT4 + lclamp];
            #pragma unroll
            for (int jj = 0; jj < MLP; ++jj) {
                const float qq = qs[jj];
                if (jj & 1) {
                    accO.x = fmaf(r[jj].x, qq, accO.x);
                    accO.y = fmaf(r[jj].y, qq, accO.y);
                    accO.z = fmaf(r[jj].z, qq, accO.z);
                    accO.w = fmaf(r[jj].w, qq, accO.w);
                } else {
                    accE.x = fmaf(r[jj].x, qq, accE.x);
                    accE.y = fmaf(r[jj].y, qq, accE.y);
                    accE.z = fmaf(r[jj].z, qq, accE.z);
                    accE.w = fmaf(r[jj].w, qq, accE.w);
                }
            }
        }
    }

    // per-wave private LDS rows (no float LDS atomics), then one global atomic per PMT
    __shared__ float sacc[NWAVE][184];
    if (lane < N_PMT4) {
        sacc[wave][lane * 4 + 0] = accE.x + accO.x;
        sacc[wave][lane * 4 + 1] = accE.y + accO.y;
        sacc[wave][lane * 4 + 2] = accE.z + accO.z;
        sacc[wave][lane * 4 + 3] = accE.w + accO.w;
    }
    __syncthreads();
    for (int i = threadIdx.x; i < N_PMT; i += BLOCK) {
        float s = sacc[0][i] + sacc[1][i] + sacc[2][i] + sacc[3][i];
        atomicAdd(&out[c * N_PMT + i], s);
    }
}

// ---------------- fallback (unsorted point-major, R3 structure) ----------------
__global__ __launch_bounds__(BLOCK) void gather_kernel(
    const float4* __restrict__ batch,
    const float4* __restrict__ vis4,
    const int*    __restrict__ offsets,
    const float*  __restrict__ dxc,
    float* __restrict__ out) {
    const int b = blockIdx.x;
    const int c = b / BPC, sub = b % BPC;
    const int start = offsets[c], end = offsets[c + 1];
    const int count = end - start;
    const int chunk = (count + BPC - 1) / BPC;
    const int s0 = start + sub * chunk;
    const int s1 = min(s0 + chunk, end);
    const int wave = threadIdx.x >> 6, lane = threadIdx.x & 63;
    const int wtotal = s1 - s0;
    const int per = (wtotal + NWAVE - 1) / NWAVE;
    const int ws0 = s0 + wave * per;
    const int ws1 = min(ws0 + per, s1);
    const float dxc_c = dxc[c];
    const bool active = (lane < N_PMT4);
    float4 accE = {0.f, 0.f, 0.f, 0.f};
    for (int base = ws0; base < ws1; base += 64) {
        const int p = base + lane;
        float q = 0.f; int vox = 0;
        if (p < ws1) {
            float4 pd = batch[p];
            int ix = max(0, min(63, (int)floorf(pd.x + dxc_c)));
            int iy = max(0, min(63, (int)floorf(pd.y)));
            int iz = max(0, min(63, (int)floorf(pd.z)));
            vox = ix + 64 * (iy + 64 * iz);
            q = pd.w;
        }
        #pragma unroll
        for (int j = 0; j < 64; ++j) {
            const int   v  = __builtin_amdgcn_readlane(vox, j);
            const float qj = __uint_as_float(__builtin_amdgcn_readlane(__float_as_uint(q), j));
            if (active) {
                float4 r = vis4[(size_t)v * N_PMT4 + lane];
                accE.x = fmaf(r.x, qj, accE.x);
                accE.y = fmaf(r.y, qj, accE.y);
                accE.z = fmaf(r.z, qj, accE.z);
                accE.w = fmaf(r.w, qj, accE.w);
            }
        }
    }
    __shared__ float sacc[N_PMT];
    for (int i = threadIdx.x; i < N_PMT; i += BLOCK) sacc[i] = 0.f;
    __syncthreads();
    if (active) {
        atomicAdd(&sacc[lane * 4 + 0], accE.x);
        atomicAdd(&sacc[lane * 4 + 1], accE.y);
        atomicAdd(&sacc[lane * 4 + 2], accE.z);
        atomicAdd(&sacc[lane * 4 + 3], accE.w);
    }
    __syncthreads();
    for (int i = threadIdx.x; i < N_PMT; i += BLOCK)
        atomicAdd(&out[c * N_PMT + i], sacc[i]);
}

extern "C" void kernel_launch(void* const* d_in, const int* in_sizes, int n_in,
                              void* d_out, int out_size, void* d_ws, size_t ws_size,
                              hipStream_t stream) {
    const float* dx        = (const float*)d_in[0];
    const float* batch     = (const float*)d_in[1];
    const int*   sizes     = (const int*)d_in[2];
    const float* dx_ranges = (const float*)d_in[3];
    const float* vis       = (const float*)d_in[4];
    float* out = (float*)d_out;
    char*  wsb = (char*)d_ws;
    const int n = in_sizes[1] / 4;   // total points

    int*   offsC  = (int*)(wsb + 0);
    float* dxc    = (float*)(wsb + 1024);
    uint2* vq     = (uint2*)(wsb + 2048);
    uint2* sorted = (uint2*)(wsb + 2048 + (size_t)8 * n);

    hipMemsetAsync(out, 0, (size_t)out_size * sizeof(float), stream);
    prep_kernel<<<1, N_CLUSTERS, 0, stream>>>(dx, sizes, dx_ranges, offsC, dxc);

    const size_t need = 2048ull + 16ull * (size_t)n;
    if (ws_size >= need) {
        k1_voxelize<<<(n + 255) / 256, 256, 0, stream>>>(
            (const float4*)batch, offsC, dxc, n, vq);
        ksort<<<N_CLUSTERS, 1024, 0, stream>>>(offsC, vq, sorted);
        k_gather<<<N_CLUSTERS * BPC, BLOCK, 0, stream>>>(
            sorted, (const float4*)vis, offsC, out);
    } else {
        gather_kernel<<<N_CLUSTERS * BPC, BLOCK, 0, stream>>>(
            (const float4*)batch, (const float4*)vis, offsC, dxc, out);
    }
}

// Round 6
// 329.916 us; speedup vs baseline: 3.9478x; 1.0326x over previous
//
#include <hip/hip_runtime.h>

#define N_PMT 180
#define N_PMT4 45          // 180 floats = 45 float4 per vis row (720 B, 16B-aligned)
#define N_CLUSTERS 128
#define NBINS 512          // sort buckets: vox >> 9
#define BPC 32             // gather blocks per cluster (chunk = 256 points)
#define BLOCK 256
#define NWAVE (BLOCK / 64)
#define PIPE 4             // software-pipeline depth (rows in flight)

// ---- workspace layout (bytes) ----
// 0       : int   offsC[N_CLUSTERS+1]
// 1024    : float dxc[N_CLUSTERS]
// 2048    : uint2 vq[n]        (vox, q_bits)  cluster-contiguous
// 2048+8n : uint2 sorted[n]    (vox, q_bits)  bucket-sorted within cluster

__global__ void prep_kernel(const float* __restrict__ dx,
                            const int* __restrict__ sizes,
                            const float* __restrict__ dx_ranges,
                            int* __restrict__ offsC,
                            float* __restrict__ dxc) {
    __shared__ int s[N_CLUSTERS];
    const int t = threadIdx.x;      // 128 threads
    s[t] = sizes[t];
    float lo = dx_ranges[2 * t];
    float hi = dx_ranges[2 * t + 1];
    dxc[t] = fminf(fmaxf(dx[t], lo), hi);
    __syncthreads();
    int acc = 0;
    for (int i = 0; i < t; ++i) acc += s[i];
    offsC[t] = acc;
    if (t == N_CLUSTERS - 1) offsC[N_CLUSTERS] = acc + s[t];
}

__global__ void k1_voxelize(const float4* __restrict__ batch,
                            const int* __restrict__ offsC,
                            const float* __restrict__ dxc,
                            int n, uint2* __restrict__ vq) {
    int i = blockIdx.x * 256 + threadIdx.x;
    if (i >= n) return;
    int lo = 0, hi = N_CLUSTERS - 1;
    #pragma unroll
    for (int s = 0; s < 7; ++s) {
        int mid = (lo + hi + 1) >> 1;
        if (i >= offsC[mid]) lo = mid; else hi = mid - 1;
    }
    float4 pd = batch[i];
    int ix = max(0, min(63, (int)floorf(pd.x + dxc[lo])));
    int iy = max(0, min(63, (int)floorf(pd.y)));
    int iz = max(0, min(63, (int)floorf(pd.z)));
    vq[i] = make_uint2((unsigned)(ix + 64 * (iy + 64 * iz)), __float_as_uint(pd.w));
}

// one block per cluster: single-pass counting sort by vox>>9 (int LDS atomics only)
__global__ __launch_bounds__(1024) void ksort(const int* __restrict__ offsC,
                                              const uint2* __restrict__ vq,
                                              uint2* __restrict__ sorted) {
    __shared__ int hist[NBINS], sa[NBINS], sb[NBINS], cur[NBINS];
    const int c = blockIdx.x, t = threadIdx.x;
    const int e0 = offsC[c], e1 = offsC[c + 1], cnt = e1 - e0;
    if (t < NBINS) hist[t] = 0;
    __syncthreads();
    for (int i = t; i < cnt; i += 1024)
        atomicAdd(&hist[vq[e0 + i].x >> 9], 1);
    __syncthreads();
    if (t < NBINS) sa[t] = hist[t];
    __syncthreads();
    int* src = sa; int* dst = sb;
    for (int d = 1; d < NBINS; d <<= 1) {
        if (t < NBINS) dst[t] = src[t] + (t >= d ? src[t - d] : 0);
        __syncthreads();
        int* tmp = src; src = dst; dst = tmp;
    }
    if (t < NBINS) cur[t] = src[t] - hist[t];   // exclusive scan
    __syncthreads();
    for (int i = t; i < cnt; i += 1024) {
        uint2 e = vq[e0 + i];
        int pos = atomicAdd(&cur[e.x >> 9], 1);
        sorted[e0 + pos] = e;
    }
}

__global__ __launch_bounds__(BLOCK) void k_gather(
    const uint2*  __restrict__ sorted,
    const float4* __restrict__ vis4,
    const int*    __restrict__ offsC,
    float* __restrict__ out) {

    const int c   = blockIdx.x & (N_CLUSTERS - 1);  // c fastest: same-region blocks adjacent
    const int sub = blockIdx.x >> 7;
    const int start = offsC[c], end = offsC[c + 1];
    const int count = end - start;
    const int chunk = (count + BPC - 1) / BPC;
    const int s0 = start + sub * chunk;
    const int s1 = min(s0 + chunk, end);

    const int wave = threadIdx.x >> 6, lane = threadIdx.x & 63;
    const int wtotal = s1 - s0;
    const int per = (wtotal + NWAVE - 1) / NWAVE;
    const int ws0 = s0 + wave * per;
    const int ws1 = min(ws0 + per, s1);

    const int lclamp = min(lane, N_PMT4 - 1);    // branchless: lanes 45..63 dup lane 44

    float4 accE = {0.f, 0.f, 0.f, 0.f};
    float4 accO = {0.f, 0.f, 0.f, 0.f};

    for (int base = ws0; base < ws1; base += 64) {
        const int p = base + lane;
        uint2 se = (p < ws1) ? sorted[p] : make_uint2(0u, 0u);  // pad: q=0
        const int   vox = (int)se.x;
        const float q   = __uint_as_float(se.y);

        // ---- software-pipelined row loads: issue batch j+1 before consuming batch j
        float4 rc[PIPE];
        #pragma unroll
        for (int jj = 0; jj < PIPE; ++jj) {
            const int v = __builtin_amdgcn_readlane(vox, jj);
            rc[jj] = vis4[(size_t)v * N_PMT4 + lclamp];
        }
        #pragma unroll
        for (int j0 = 0; j0 < 64; j0 += PIPE) {
            float4 rn[PIPE];
            if (j0 + PIPE < 64) {
                #pragma unroll
                for (int jj = 0; jj < PIPE; ++jj) {
                    const int v = __builtin_amdgcn_readlane(vox, j0 + PIPE + jj);
                    rn[jj] = vis4[(size_t)v * N_PMT4 + lclamp];
                }
            }
            #pragma unroll
            for (int jj = 0; jj < PIPE; ++jj) {
                const float qq = __uint_as_float(
                    __builtin_amdgcn_readlane(__float_as_uint(q), j0 + jj));
                if (jj & 1) {
                    accO.x = fmaf(rc[jj].x, qq, accO.x);
                    accO.y = fmaf(rc[jj].y, qq, accO.y);
                    accO.z = fmaf(rc[jj].z, qq, accO.z);
                    accO.w = fmaf(rc[jj].w, qq, accO.w);
                } else {
                    accE.x = fmaf(rc[jj].x, qq, accE.x);
                    accE.y = fmaf(rc[jj].y, qq, accE.y);
                    accE.z = fmaf(rc[jj].z, qq, accE.z);
                    accE.w = fmaf(rc[jj].w, qq, accE.w);
                }
            }
            #pragma unroll
            for (int jj = 0; jj < PIPE; ++jj) rc[jj] = rn[jj];  // renamed under full unroll
        }
    }

    // per-wave private LDS rows (no float LDS atomics), then one global atomic per PMT
    __shared__ float sacc[NWAVE][184];
    if (lane < N_PMT4) {
        sacc[wave][lane * 4 + 0] = accE.x + accO.x;
        sacc[wave][lane * 4 + 1] = accE.y + accO.y;
        sacc[wave][lane * 4 + 2] = accE.z + accO.z;
        sacc[wave][lane * 4 + 3] = accE.w + accO.w;
    }
    __syncthreads();
    for (int i = threadIdx.x; i < N_PMT; i += BLOCK) {
        float s = sacc[0][i] + sacc[1][i] + sacc[2][i] + sacc[3][i];
        atomicAdd(&out[c * N_PMT + i], s);
    }
}

// ---------------- fallback (unsorted point-major, R3 structure) ----------------
__global__ __launch_bounds__(BLOCK) void gather_kernel(
    const float4* __restrict__ batch,
    const float4* __restrict__ vis4,
    const int*    __restrict__ offsets,
    const float*  __restrict__ dxc,
    float* __restrict__ out) {
    const int b = blockIdx.x;
    const int c = b / 16, sub = b % 16;
    const int start = offsets[c], end = offsets[c + 1];
    const int count = end - start;
    const int chunk = (count + 15) / 16;
    const int s0 = start + sub * chunk;
    const int s1 = min(s0 + chunk, end);
    const int wave = threadIdx.x >> 6, lane = threadIdx.x & 63;
    const int wtotal = s1 - s0;
    const int per = (wtotal + NWAVE - 1) / NWAVE;
    const int ws0 = s0 + wave * per;
    const int ws1 = min(ws0 + per, s1);
    const float dxc_c = dxc[c];
    const bool active = (lane < N_PMT4);
    float4 accE = {0.f, 0.f, 0.f, 0.f};
    for (int base = ws0; base < ws1; base += 64) {
        const int p = base + lane;
        float q = 0.f; int vox = 0;
        if (p < ws1) {
            float4 pd = batch[p];
            int ix = max(0, min(63, (int)floorf(pd.x + dxc_c)));
            int iy = max(0, min(63, (int)floorf(pd.y)));
            int iz = max(0, min(63, (int)floorf(pd.z)));
            vox = ix + 64 * (iy + 64 * iz);
            q = pd.w;
        }
        #pragma unroll
        for (int j = 0; j < 64; ++j) {
            const int   v  = __builtin_amdgcn_readlane(vox, j);
            const float qj = __uint_as_float(__builtin_amdgcn_readlane(__float_as_uint(q), j));
            if (active) {
                float4 r = vis4[(size_t)v * N_PMT4 + lane];
                accE.x = fmaf(r.x, qj, accE.x);
                accE.y = fmaf(r.y, qj, accE.y);
                accE.z = fmaf(r.z, qj, accE.z);
                accE.w = fmaf(r.w, qj, accE.w);
            }
        }
    }
    __shared__ float sacc[N_PMT];
    for (int i = threadIdx.x; i < N_PMT; i += BLOCK) sacc[i] = 0.f;
    __syncthreads();
    if (active) {
        atomicAdd(&sacc[lane * 4 + 0], accE.x);
        atomicAdd(&sacc[lane * 4 + 1], accE.y);
        atomicAdd(&sacc[lane * 4 + 2], accE.z);
        atomicAdd(&sacc[lane * 4 + 3], accE.w);
    }
    __syncthreads();
    for (int i = threadIdx.x; i < N_PMT; i += BLOCK)
        atomicAdd(&out[c * N_PMT + i], sacc[i]);
}

extern "C" void kernel_launch(void* const* d_in, const int* in_sizes, int n_in,
                              void* d_out, int out_size, void* d_ws, size_t ws_size,
                              hipStream_t stream) {
    const float* dx        = (const float*)d_in[0];
    const float* batch     = (const float*)d_in[1];
    const int*   sizes     = (const int*)d_in[2];
    const float* dx_ranges = (const float*)d_in[3];
    const float* vis       = (const float*)d_in[4];
    float* out = (float*)d_out;
    char*  wsb = (char*)d_ws;
    const int n = in_sizes[1] / 4;   // total points

    int*   offsC  = (int*)(wsb + 0);
    float* dxc    = (float*)(wsb + 1024);
    uint2* vq     = (uint2*)(wsb + 2048);
    uint2* sorted = (uint2*)(wsb + 2048 + (size_t)8 * n);

    hipMemsetAsync(out, 0, (size_t)out_size * sizeof(float), stream);
    prep_kernel<<<1, N_CLUSTERS, 0, stream>>>(dx, sizes, dx_ranges, offsC, dxc);

    const size_t need = 2048ull + 16ull * (size_t)n;
    if (ws_size >= need) {
        k1_voxelize<<<(n + 255) / 256, 256, 0, stream>>>(
            (const float4*)batch, offsC, dxc, n, vq);
        ksort<<<N_CLUSTERS, 1024, 0, stream>>>(offsC, vq, sorted);
        k_gather<<<N_CLUSTERS * BPC, BLOCK, 0, stream>>>(
            sorted, (const float4*)vis, offsC, out);
    } else {
        gather_kernel<<<N_CLUSTERS * 16, BLOCK, 0, stream>>>(
            (const float4*)batch, (const float4*)vis, offsC, dxc, out);
    }
}